// Round 8
// baseline (486.949 us; speedup 1.0000x reference)
//
#include <hip/hip_runtime.h>

typedef unsigned short u16;
typedef unsigned int u32;
typedef __attribute__((ext_vector_type(8))) short short8;
typedef __attribute__((ext_vector_type(4))) float float4v;

#define N_NODES 100000
#define N_EDGES 1600000
#define N_PAIRS 100000
// two-level CSR: bucket = dst >> 9 -> 196 buckets of 512 nodes (~8163 edges each)
#define NBUCKP 256
#define NB_USED 196
#define BUCK_CAP 8704
#define BIN_GRID 391

__device__ __forceinline__ float bf2f(u32 lo16) {
    union { u32 u; float f; } v;
    v.u = lo16 << 16;
    return v.f;
}
__device__ __forceinline__ u16 f2bf(float f) {
    union { float f; u32 u; } v;
    v.f = f;
    u32 r = v.u + 0x7fffu + ((v.u >> 16) & 1u);
    return (u16)(r >> 16);
}

// ---------------- CSR build ----------------
__global__ void k_binit(int* bucket_cur) {
    bucket_cur[threadIdx.x] = threadIdx.x * BUCK_CAP;
}

__global__ __launch_bounds__(256) void k_bin(const int* __restrict__ esrc, const int* __restrict__ edst,
                                             int* bucket_cur, int2* __restrict__ binned) {
    __shared__ int cnt[NBUCKP];
    __shared__ int base[NBUCKP];
    int t = threadIdx.x;
    cnt[t] = 0;
    __syncthreads();
    int s[16], d[16], r[16];
    int e0 = blockIdx.x * 4096;
#pragma unroll
    for (int k = 0; k < 16; k++) {
        int e = e0 + k * 256 + t;
        if (e < N_EDGES) {
            s[k] = esrc[e];
            d[k] = edst[e];
            r[k] = atomicAdd(&cnt[d[k] >> 9], 1);
        } else {
            d[k] = -1;
        }
    }
    __syncthreads();
    base[t] = cnt[t] ? atomicAdd(&bucket_cur[t], cnt[t]) : 0;
    __syncthreads();
#pragma unroll
    for (int k = 0; k < 16; k++) {
        if (d[k] >= 0) {
            int bk = d[k] >> 9;
            int pos = base[bk] + r[k];
            if (pos < (bk + 1) * BUCK_CAP)
                binned[pos] = make_int2(s[k], d[k]);
        }
    }
}

__global__ void k_bscan(const int* __restrict__ bucket_cur,
                        int* __restrict__ bstart, int* __restrict__ bfill) {
    __shared__ int sm[NBUCKP];
    int t = threadIdx.x;
    int v = bucket_cur[t] - t * BUCK_CAP;
    bfill[t] = v;
    sm[t] = v;
    __syncthreads();
    for (int o = 1; o < NBUCKP; o <<= 1) {
        int x = (t >= o) ? sm[t - o] : 0;
        __syncthreads();
        sm[t] += x;
        __syncthreads();
    }
    bstart[t] = sm[t] - v;
}

__global__ __launch_bounds__(512) void k_sort(const int2* __restrict__ binned,
                                              const int* __restrict__ bstart,
                                              const int* __restrict__ bfill,
                                              int* __restrict__ row_ptr,
                                              int2* __restrict__ col_sd) {
    __shared__ int cnt[512];
    __shared__ int sm[512];
    int b = blockIdx.x, t = threadIdx.x;
    cnt[t] = 0;
    __syncthreads();
    const int2* ebase = binned + (size_t)b * BUCK_CAP;
    int n_e = bfill[b];
    if (n_e > BUCK_CAP) n_e = BUCK_CAP;
    for (int i = t; i < n_e; i += 512)
        atomicAdd(&cnt[ebase[i].y & 511], 1);
    __syncthreads();
    int v = cnt[t];
    sm[t] = v;
    __syncthreads();
    for (int o = 1; o < 512; o <<= 1) {
        int x = (t >= o) ? sm[t - o] : 0;
        __syncthreads();
        sm[t] += x;
        __syncthreads();
    }
    int base = bstart[b];
    int excl = base + sm[t] - v;
    int node = b * 512 + t;
    if (node <= N_NODES) row_ptr[node] = excl;
    cnt[t] = excl;
    __syncthreads();
    for (int i = t; i < n_e; i += 512) {
        int2 sd = ebase[i];
        int p = atomicAdd(&cnt[sd.y & 511], 1);
        col_sd[p] = sd;
    }
}

// ---------------- pre-swizzle weights into MFMA B-fragment order ----------------
__global__ __launch_bounds__(256) void k_prepB4(const float* __restrict__ W1, const float* __restrict__ W2,
                                                const float* __restrict__ WA, const float* __restrict__ WB,
                                                u16* __restrict__ B1, u16* __restrict__ B2,
                                                u16* __restrict__ BA, u16* __restrict__ BB) {
    int w = blockIdx.x >> 3;
    const float* W = (w == 0) ? W1 : (w == 1) ? W2 : (w == 2) ? WA : WB;
    u16* Bf = (w == 0) ? B1 : (w == 1) ? B2 : (w == 2) ? BA : BB;
    int t = (blockIdx.x & 7) * 256 + threadIdx.x;
    int kk = t >> 9, tn = (t >> 6) & 7, quad = (t >> 4) & 3, l15 = t & 15;
#pragma unroll
    for (int j = 0; j < 8; j++) {
        int k = kk * 32 + quad * 8 + j;
        int n = tn * 16 + l15;
        Bf[(size_t)t * 8 + j] = f2bf(W[k * 128 + n]);
    }
}

// ---------------- MFMA GEMM with fused alpha epilogue ----------------
// ALPHA: also emit al_s[gr,h] = C[gr]·a_src[h], al_d likewise (per-head dot of the
// row the quad already holds: head hd covers cols [hd*32, hd*32+32) = tn {2hd, 2hd+1}).
template<bool AF32, bool DUAL, bool ALPHA>
__global__ __launch_bounds__(256) void k_gemm(const void* __restrict__ Ap,
                                              const u16* __restrict__ Bf,
                                              const u16* __restrict__ Bf2,
                                              u16* __restrict__ C,
                                              u16* __restrict__ C2,
                                              const float* __restrict__ a_src,
                                              const float* __restrict__ a_dst,
                                              float* __restrict__ al_s,
                                              float* __restrict__ al_d, int M) {
    int wave = threadIdx.x >> 6, lane = threadIdx.x & 63;
    int quad = lane >> 4, l15 = lane & 15;
    int row0 = blockIdx.x * 64 + wave * 16;
    int m = row0 + l15;
    int mload = (m < M) ? m : (M - 1);

    short8 a[4];
    if (AF32) {
        const float* A = (const float*)Ap;
#pragma unroll
        for (int kk = 0; kk < 4; kk++) {
            const float* p = A + (size_t)mload * 128 + kk * 32 + quad * 8;
            float4 f0 = *(const float4*)p;
            float4 f1 = *(const float4*)(p + 4);
            short8 av;
            av[0] = (short)f2bf(f0.x); av[1] = (short)f2bf(f0.y);
            av[2] = (short)f2bf(f0.z); av[3] = (short)f2bf(f0.w);
            av[4] = (short)f2bf(f1.x); av[5] = (short)f2bf(f1.y);
            av[6] = (short)f2bf(f1.z); av[7] = (short)f2bf(f1.w);
            a[kk] = av;
        }
    } else {
        const u16* A = (const u16*)Ap;
#pragma unroll
        for (int kk = 0; kk < 4; kk++)
            a[kk] = *(const short8*)(A + (size_t)mload * 128 + kk * 32 + quad * 8);
    }

    float4v acc[8], acc2[8];
#pragma unroll
    for (int tn = 0; tn < 8; tn++) {
        acc[tn] = (float4v){0.f, 0.f, 0.f, 0.f};
        if (DUAL) acc2[tn] = (float4v){0.f, 0.f, 0.f, 0.f};
    }

#pragma unroll
    for (int kk = 0; kk < 4; kk++) {
#pragma unroll
        for (int tn = 0; tn < 8; tn++) {
            short8 b = *(const short8*)(Bf + ((size_t)((kk * 8 + tn) * 64 + lane)) * 8);
            acc[tn] = __builtin_amdgcn_mfma_f32_16x16x32_bf16(a[kk], b, acc[tn], 0, 0, 0);
            if (DUAL) {
                short8 b2 = *(const short8*)(Bf2 + ((size_t)((kk * 8 + tn) * 64 + lane)) * 8);
                acc2[tn] = __builtin_amdgcn_mfma_f32_16x16x32_bf16(a[kk], b2, acc2[tn], 0, 0, 0);
            }
        }
    }

    float as0[4], as1[4], ad0[4], ad1[4];
    if (ALPHA) {
#pragma unroll
        for (int hd = 0; hd < 4; hd++) {
            as0[hd] = a_src[hd * 32 + l15];
            as1[hd] = a_src[hd * 32 + 16 + l15];
            ad0[hd] = a_dst[hd * 32 + l15];
            ad1[hd] = a_dst[hd * 32 + 16 + l15];
        }
    }

#pragma unroll
    for (int rg = 0; rg < 4; rg++) {
        int gr = row0 + quad * 4 + rg;
        bool ok = (gr < M);
        if (ok) {
#pragma unroll
            for (int tn = 0; tn < 8; tn++) {
                C[(size_t)gr * 128 + tn * 16 + l15] = f2bf(acc[tn][rg]);
                if (DUAL) C2[(size_t)gr * 128 + tn * 16 + l15] = f2bf(acc2[tn][rg]);
            }
        }
        if (ALPHA) {
            // per-head partial dots (use the bf16-rounded values to match h exactly)
            float ps[4], pd[4];
#pragma unroll
            for (int hd = 0; hd < 4; hd++) {
                float c0 = bf2f((u32)(u16)f2bf(acc[2 * hd][rg]));
                float c1 = bf2f((u32)(u16)f2bf(acc[2 * hd + 1][rg]));
                ps[hd] = c0 * as0[hd] + c1 * as1[hd];
                pd[hd] = c0 * ad0[hd] + c1 * ad1[hd];
            }
#pragma unroll
            for (int mm = 1; mm < 16; mm <<= 1) {
#pragma unroll
                for (int hd = 0; hd < 4; hd++) {
                    ps[hd] += __shfl_xor(ps[hd], mm, 64);
                    pd[hd] += __shfl_xor(pd[hd], mm, 64);
                }
            }
            if (ok && l15 < 4) {
                float vs = (l15 == 0) ? ps[0] : (l15 == 1) ? ps[1] : (l15 == 2) ? ps[2] : ps[3];
                float vd = (l15 == 0) ? pd[0] : (l15 == 1) ? pd[1] : (l15 == 2) ? pd[2] : pd[3];
                al_s[gr * 4 + l15] = vs;
                al_d[gr * 4 + l15] = vd;
            }
        }
    }
}

// ---------------- fused aggregation: scores + softmax-sum + weighted gather + elu + residual ----------------
template<bool XF32>
__global__ void k_agg(const int* __restrict__ row_ptr, const int2* __restrict__ col_sd,
                      const float* __restrict__ al_s, const float* __restrict__ al_d,
                      const u16* __restrict__ h, const void* __restrict__ xin,
                      u16* __restrict__ xout) {
    int node = blockIdx.x * 4 + (threadIdx.x >> 6);
    int lane = threadIdx.x & 63;
    int beg = row_ptr[node], end = row_ptr[node + 1];
    const int* col_s = (const int*)col_sd;  // .x at stride 2

    // sum pass: lane covers edge slot (lane>>2), head (lane&3)
    int hd = lane & 3;
    float adst_e = al_d[node * 4 + hd];
    float sum = 0.f;
    for (int i = beg + (lane >> 2); i < end; i += 16) {
        int s = __builtin_nontemporal_load(col_s + 2 * i);
        float e = al_s[s * 4 + hd] + adst_e;
        e = (e >= 0.f) ? e : 0.2f * e;
        sum += __expf(e);
    }
#pragma unroll
    for (int mm = 4; mm < 64; mm <<= 1) sum += __shfl_xor(sum, mm, 64);

    int hq = lane >> 4;
    float sh = __shfl(sum, hq, 64);
    float inv = 1.f / (sh + 1e-10f);
    float adq = al_d[node * 4 + hq];

    // weighted gather, 4 independent chains; w recomputed (f32-exact vs sum pass)
    float a0[4] = {0.f, 0.f, 0.f, 0.f};
    float a1[4] = {0.f, 0.f, 0.f, 0.f};
    int i = beg;
    for (; i + 3 < end; i += 4) {
#pragma unroll
        for (int k = 0; k < 4; k++) {
            int s = __builtin_nontemporal_load(col_s + 2 * (i + k));
            float e = al_s[s * 4 + hq] + adq;
            e = (e >= 0.f) ? e : 0.2f * e;
            float w = __expf(e);
            u32 hv = *(const u32*)&h[(size_t)s * 128 + lane * 2];
            a0[k] += w * bf2f(hv & 0xffff);
            a1[k] += w * bf2f(hv >> 16);
        }
    }
    for (; i < end; i++) {
        int s = __builtin_nontemporal_load(col_s + 2 * i);
        float e = al_s[s * 4 + hq] + adq;
        e = (e >= 0.f) ? e : 0.2f * e;
        float w = __expf(e);
        u32 hv = *(const u32*)&h[(size_t)s * 128 + lane * 2];
        a0[0] += w * bf2f(hv & 0xffff);
        a1[0] += w * bf2f(hv >> 16);
    }
    float acc0 = ((a0[0] + a0[1]) + (a0[2] + a0[3])) * inv;
    float acc1 = ((a1[0] + a1[1]) + (a1[2] + a1[3])) * inv;

    float r0, r1;
    if (XF32) {
        const float* x = (const float*)xin;
        r0 = __builtin_nontemporal_load(x + (size_t)node * 128 + lane * 2);
        r1 = __builtin_nontemporal_load(x + (size_t)node * 128 + lane * 2 + 1);
    } else {
        const u16* x = (const u16*)xin;
        u32 xv = *(const u32*)&x[(size_t)node * 128 + lane * 2];
        r0 = bf2f(xv & 0xffff);
        r1 = bf2f(xv >> 16);
    }
    float o0 = ((acc0 > 0.f) ? acc0 : (__expf(acc0) - 1.f)) + r0;
    float o1 = ((acc1 > 0.f) ? acc1 : (__expf(acc1) - 1.f)) + r1;
    xout[(size_t)node * 128 + lane * 2]     = f2bf(o0);
    xout[(size_t)node * 128 + lane * 2 + 1] = f2bf(o1);
}

// ---------------- link predictor ----------------
__global__ void k_pair(const int* __restrict__ psrc, const int* __restrict__ pdst,
                       const u16* __restrict__ u, const u16* __restrict__ v,
                       const float* __restrict__ b1, const float* __restrict__ w2,
                       const float* __restrict__ b2, float* __restrict__ out) {
    int p = blockIdx.x * 4 + (threadIdx.x >> 6);
    int lane = threadIdx.x & 63;
    int s = psrc[p], d = pdst[p];
    float h0 = bf2f(u[(size_t)s * 128 + lane * 2])     + bf2f(v[(size_t)d * 128 + lane * 2])     + b1[lane * 2];
    float h1 = bf2f(u[(size_t)s * 128 + lane * 2 + 1]) + bf2f(v[(size_t)d * 128 + lane * 2 + 1]) + b1[lane * 2 + 1];
    h0 = (h0 > 0.f) ? h0 : 0.f;
    h1 = (h1 > 0.f) ? h1 : 0.f;
    float acc = h0 * w2[lane * 2] + h1 * w2[lane * 2 + 1];
#pragma unroll
    for (int m = 1; m < 64; m <<= 1) acc += __shfl_xor(acc, m, 64);
    if (lane == 0) out[p] = acc + b2[0];
}

extern "C" void kernel_launch(void* const* d_in, const int* in_sizes, int n_in,
                              void* d_out, int out_size, void* d_ws, size_t ws_size,
                              hipStream_t stream) {
    const float* embed  = (const float*)d_in[0];
    const float* W1     = (const float*)d_in[1];
    const float* a_src1 = (const float*)d_in[2];
    const float* a_dst1 = (const float*)d_in[3];
    const float* W2     = (const float*)d_in[4];
    const float* a_src2 = (const float*)d_in[5];
    const float* a_dst2 = (const float*)d_in[6];
    const float* lp_w1  = (const float*)d_in[7];
    const float* lp_b1  = (const float*)d_in[8];
    const float* lp_w2  = (const float*)d_in[9];
    const float* lp_b2  = (const float*)d_in[10];
    const int*   edge   = (const int*)d_in[11];
    const int*   lsrc   = (const int*)d_in[12];
    const int*   ldst   = (const int*)d_in[13];
    float* out = (float*)d_out;

    char* ws = (char*)d_ws;
    size_t off = 0;
    auto alloc = [&](size_t bytes) -> char* {
        char* p = ws + off;
        off += (bytes + 255) & ~(size_t)255;
        return p;
    };
    int*  row_ptr    = (int*)alloc((N_NODES + 1) * 4);
    int*  bucket_cur = (int*)alloc(NBUCKP * 4);
    int*  bstart     = (int*)alloc(NBUCKP * 4);
    int*  bfill      = (int*)alloc(NBUCKP * 4);
    int2* binned     = (int2*)alloc((size_t)NBUCKP * BUCK_CAP * 8);
    int2* col_sd     = (int2*)alloc((size_t)N_EDGES * 8);
    u16*  h          = (u16*)alloc((size_t)N_NODES * 128 * 2);
    float* al_s      = (float*)alloc((size_t)N_NODES * 4 * 4);
    float* al_d      = (float*)alloc((size_t)N_NODES * 4 * 4);
    u16*  x1         = (u16*)alloc((size_t)N_NODES * 128 * 2);
    u16*  z          = (u16*)alloc((size_t)N_NODES * 128 * 2);
    u16*  Bf1        = (u16*)alloc(128 * 128 * 2);
    u16*  Bf2        = (u16*)alloc(128 * 128 * 2);
    u16*  BfA        = (u16*)alloc(128 * 128 * 2);
    u16*  BfB        = (u16*)alloc(128 * 128 * 2);
    u16* uu = h;    // reuse: h dead after layer-2 aggregation
    u16* vv = x1;   // reuse: x1 dead after layer-2 aggregation

    const int* esrc = edge;
    const int* edst = edge + N_EDGES;
    const int GB = (N_NODES + 63) / 64;

    k_prepB4<<<32, 256, 0, stream>>>(W1, W2, lp_w1, lp_w1 + 128 * 128, Bf1, Bf2, BfA, BfB);

    k_binit<<<1, NBUCKP, 0, stream>>>(bucket_cur);
    k_bin  <<<BIN_GRID, 256, 0, stream>>>(esrc, edst, bucket_cur, binned);
    k_bscan<<<1, NBUCKP, 0, stream>>>(bucket_cur, bstart, bfill);
    k_sort <<<NB_USED, 512, 0, stream>>>(binned, bstart, bfill, row_ptr, col_sd);

    // layer 1: h = embed @ W1 (+ fused alpha)
    k_gemm<true, false, true><<<GB, 256, 0, stream>>>(embed, Bf1, nullptr, h, nullptr,
                                                      a_src1, a_dst1, al_s, al_d, N_NODES);
    k_agg<true><<<N_NODES / 4, 256, 0, stream>>>(row_ptr, col_sd, al_s, al_d, h, embed, x1);
    // layer 2: h = x1 @ W2 (+ fused alpha)
    k_gemm<false, false, true><<<GB, 256, 0, stream>>>(x1, Bf2, nullptr, h, nullptr,
                                                       a_src2, a_dst2, al_s, al_d, N_NODES);
    k_agg<false><<<N_NODES / 4, 256, 0, stream>>>(row_ptr, col_sd, al_s, al_d, h, x1, z);
    // link predictor
    k_gemm<false, true, false><<<GB, 256, 0, stream>>>(z, BfA, BfB, uu, vv,
                                                       nullptr, nullptr, nullptr, nullptr, N_NODES);
    k_pair<<<N_PAIRS / 4, 256, 0, stream>>>(lsrc, ldst, uu, vv, lp_b1, lp_w2, lp_b2, out);
}

// Round 9
// 458.957 us; speedup vs baseline: 1.0610x; 1.0610x over previous
//
#include <hip/hip_runtime.h>

typedef unsigned short u16;
typedef unsigned int u32;
typedef __attribute__((ext_vector_type(8))) short short8;
typedef __attribute__((ext_vector_type(4))) float float4v;

#define N_NODES 100000
#define N_EDGES 1600000
#define N_PAIRS 100000
#define NBUCKP 256
#define NB_USED 196
#define BUCK_CAP 8704
#define BIN_GRID 391

__device__ __forceinline__ float bf2f(u32 lo16) {
    union { u32 u; float f; } v;
    v.u = lo16 << 16;
    return v.f;
}
__device__ __forceinline__ u16 f2bf(float f) {
    union { float f; u32 u; } v;
    v.f = f;
    u32 r = v.u + 0x7fffu + ((v.u >> 16) & 1u);
    return (u16)(r >> 16);
}

// ---------------- CSR build ----------------
__global__ void k_binit(int* bucket_cur) {
    bucket_cur[threadIdx.x] = threadIdx.x * BUCK_CAP;
}

__global__ __launch_bounds__(256) void k_bin(const int* __restrict__ esrc, const int* __restrict__ edst,
                                             int* bucket_cur, int2* __restrict__ binned) {
    __shared__ int cnt[NBUCKP];
    __shared__ int base[NBUCKP];
    int t = threadIdx.x;
    cnt[t] = 0;
    __syncthreads();
    int s[16], d[16], r[16];
    int e0 = blockIdx.x * 4096;
#pragma unroll
    for (int k = 0; k < 16; k++) {
        int e = e0 + k * 256 + t;
        if (e < N_EDGES) {
            s[k] = esrc[e];
            d[k] = edst[e];
            r[k] = atomicAdd(&cnt[d[k] >> 9], 1);
        } else {
            d[k] = -1;
        }
    }
    __syncthreads();
    base[t] = cnt[t] ? atomicAdd(&bucket_cur[t], cnt[t]) : 0;
    __syncthreads();
#pragma unroll
    for (int k = 0; k < 16; k++) {
        if (d[k] >= 0) {
            int bk = d[k] >> 9;
            int pos = base[bk] + r[k];
            if (pos < (bk + 1) * BUCK_CAP)
                binned[pos] = make_int2(s[k], d[k]);
        }
    }
}

__global__ void k_bscan(const int* __restrict__ bucket_cur,
                        int* __restrict__ bstart, int* __restrict__ bfill) {
    __shared__ int sm[NBUCKP];
    int t = threadIdx.x;
    int v = bucket_cur[t] - t * BUCK_CAP;
    bfill[t] = v;
    sm[t] = v;
    __syncthreads();
    for (int o = 1; o < NBUCKP; o <<= 1) {
        int x = (t >= o) ? sm[t - o] : 0;
        __syncthreads();
        sm[t] += x;
        __syncthreads();
    }
    bstart[t] = sm[t] - v;
}

__global__ __launch_bounds__(512) void k_sort(const int2* __restrict__ binned,
                                              const int* __restrict__ bstart,
                                              const int* __restrict__ bfill,
                                              int* __restrict__ row_ptr,
                                              int2* __restrict__ col_sd,
                                              int* __restrict__ col_src) {
    __shared__ int cnt[512];
    __shared__ int sm[512];
    int b = blockIdx.x, t = threadIdx.x;
    cnt[t] = 0;
    __syncthreads();
    const int2* ebase = binned + (size_t)b * BUCK_CAP;
    int n_e = bfill[b];
    if (n_e > BUCK_CAP) n_e = BUCK_CAP;
    for (int i = t; i < n_e; i += 512)
        atomicAdd(&cnt[ebase[i].y & 511], 1);
    __syncthreads();
    int v = cnt[t];
    sm[t] = v;
    __syncthreads();
    for (int o = 1; o < 512; o <<= 1) {
        int x = (t >= o) ? sm[t - o] : 0;
        __syncthreads();
        sm[t] += x;
        __syncthreads();
    }
    int base = bstart[b];
    int excl = base + sm[t] - v;
    int node = b * 512 + t;
    if (node <= N_NODES) row_ptr[node] = excl;
    cnt[t] = excl;
    __syncthreads();
    for (int i = t; i < n_e; i += 512) {
        int2 sd = ebase[i];
        int p = atomicAdd(&cnt[sd.y & 511], 1);
        col_sd[p] = sd;
        col_src[p] = sd.x;
    }
}

// ---------------- pre-swizzle weights into MFMA B-fragment order ----------------
__global__ __launch_bounds__(256) void k_prepB4(const float* __restrict__ W1, const float* __restrict__ W2,
                                                const float* __restrict__ WA, const float* __restrict__ WB,
                                                u16* __restrict__ B1, u16* __restrict__ B2,
                                                u16* __restrict__ BA, u16* __restrict__ BB) {
    int w = blockIdx.x >> 3;
    const float* W = (w == 0) ? W1 : (w == 1) ? W2 : (w == 2) ? WA : WB;
    u16* Bf = (w == 0) ? B1 : (w == 1) ? B2 : (w == 2) ? BA : BB;
    int t = (blockIdx.x & 7) * 256 + threadIdx.x;
    int kk = t >> 9, tn = (t >> 6) & 7, quad = (t >> 4) & 3, l15 = t & 15;
#pragma unroll
    for (int j = 0; j < 8; j++) {
        int k = kk * 32 + quad * 8 + j;
        int n = tn * 16 + l15;
        Bf[(size_t)t * 8 + j] = f2bf(W[k * 128 + n]);
    }
}

// ---------------- MFMA GEMM with fused alpha epilogue ----------------
template<bool AF32, bool DUAL, bool ALPHA>
__global__ __launch_bounds__(256) void k_gemm(const void* __restrict__ Ap,
                                              const u16* __restrict__ Bf,
                                              const u16* __restrict__ Bf2,
                                              u16* __restrict__ C,
                                              u16* __restrict__ C2,
                                              const float* __restrict__ a_src,
                                              const float* __restrict__ a_dst,
                                              float* __restrict__ al_s,
                                              float* __restrict__ al_d, int M) {
    int wave = threadIdx.x >> 6, lane = threadIdx.x & 63;
    int quad = lane >> 4, l15 = lane & 15;
    int row0 = blockIdx.x * 64 + wave * 16;
    int m = row0 + l15;
    int mload = (m < M) ? m : (M - 1);

    short8 a[4];
    if (AF32) {
        const float* A = (const float*)Ap;
#pragma unroll
        for (int kk = 0; kk < 4; kk++) {
            const float* p = A + (size_t)mload * 128 + kk * 32 + quad * 8;
            float4 f0 = *(const float4*)p;
            float4 f1 = *(const float4*)(p + 4);
            short8 av;
            av[0] = (short)f2bf(f0.x); av[1] = (short)f2bf(f0.y);
            av[2] = (short)f2bf(f0.z); av[3] = (short)f2bf(f0.w);
            av[4] = (short)f2bf(f1.x); av[5] = (short)f2bf(f1.y);
            av[6] = (short)f2bf(f1.z); av[7] = (short)f2bf(f1.w);
            a[kk] = av;
        }
    } else {
        const u16* A = (const u16*)Ap;
#pragma unroll
        for (int kk = 0; kk < 4; kk++)
            a[kk] = *(const short8*)(A + (size_t)mload * 128 + kk * 32 + quad * 8);
    }

    float4v acc[8], acc2[8];
#pragma unroll
    for (int tn = 0; tn < 8; tn++) {
        acc[tn] = (float4v){0.f, 0.f, 0.f, 0.f};
        if (DUAL) acc2[tn] = (float4v){0.f, 0.f, 0.f, 0.f};
    }

#pragma unroll
    for (int kk = 0; kk < 4; kk++) {
#pragma unroll
        for (int tn = 0; tn < 8; tn++) {
            short8 b = *(const short8*)(Bf + ((size_t)((kk * 8 + tn) * 64 + lane)) * 8);
            acc[tn] = __builtin_amdgcn_mfma_f32_16x16x32_bf16(a[kk], b, acc[tn], 0, 0, 0);
            if (DUAL) {
                short8 b2 = *(const short8*)(Bf2 + ((size_t)((kk * 8 + tn) * 64 + lane)) * 8);
                acc2[tn] = __builtin_amdgcn_mfma_f32_16x16x32_bf16(a[kk], b2, acc2[tn], 0, 0, 0);
            }
        }
    }

    float as0[4], as1[4], ad0[4], ad1[4];
    if (ALPHA) {
#pragma unroll
        for (int hd = 0; hd < 4; hd++) {
            as0[hd] = a_src[hd * 32 + l15];
            as1[hd] = a_src[hd * 32 + 16 + l15];
            ad0[hd] = a_dst[hd * 32 + l15];
            ad1[hd] = a_dst[hd * 32 + 16 + l15];
        }
    }

#pragma unroll
    for (int rg = 0; rg < 4; rg++) {
        int gr = row0 + quad * 4 + rg;
        bool ok = (gr < M);
        if (ok) {
#pragma unroll
            for (int tn = 0; tn < 8; tn++) {
                C[(size_t)gr * 128 + tn * 16 + l15] = f2bf(acc[tn][rg]);
                if (DUAL) C2[(size_t)gr * 128 + tn * 16 + l15] = f2bf(acc2[tn][rg]);
            }
        }
        if (ALPHA) {
            float ps[4], pd[4];
#pragma unroll
            for (int hd = 0; hd < 4; hd++) {
                float c0 = bf2f((u32)(u16)f2bf(acc[2 * hd][rg]));
                float c1 = bf2f((u32)(u16)f2bf(acc[2 * hd + 1][rg]));
                ps[hd] = c0 * as0[hd] + c1 * as1[hd];
                pd[hd] = c0 * ad0[hd] + c1 * ad1[hd];
            }
#pragma unroll
            for (int mm = 1; mm < 16; mm <<= 1) {
#pragma unroll
                for (int hd = 0; hd < 4; hd++) {
                    ps[hd] += __shfl_xor(ps[hd], mm, 64);
                    pd[hd] += __shfl_xor(pd[hd], mm, 64);
                }
            }
            if (ok && l15 < 4) {
                float vs = (l15 == 0) ? ps[0] : (l15 == 1) ? ps[1] : (l15 == 2) ? ps[2] : ps[3];
                float vd = (l15 == 0) ? pd[0] : (l15 == 1) ? pd[1] : (l15 == 2) ? pd[2] : pd[3];
                al_s[gr * 4 + l15] = vs;
                al_d[gr * 4 + l15] = vd;
            }
        }
    }
}

// ---------------- edge-parallel scores (bf16) ----------------
__global__ void k_score(const int2* __restrict__ col_sd,
                        const float* __restrict__ al_s, const float* __restrict__ al_d,
                        u16* __restrict__ w_edge) {
    int g = blockIdx.x * 256 + threadIdx.x;  // [0, 4E)
    int i = g >> 2, hd = g & 3;
    int2 sd = col_sd[i];
    float e = al_s[sd.x * 4 + hd] + al_d[sd.y * 4 + hd];
    e = (e >= 0.f) ? e : 0.2f * e;
    w_edge[g] = f2bf(__expf(e));
}

// ---------------- aggregation: coalesced sum pass + weighted gather (8 chains) ----------------
template<bool XF32>
__global__ void k_agg(const int* __restrict__ row_ptr, const int* __restrict__ col_src,
                      const u16* __restrict__ w_edge,
                      const u16* __restrict__ h, const void* __restrict__ xin,
                      u16* __restrict__ xout) {
    int node = blockIdx.x * 4 + (threadIdx.x >> 6);
    int lane = threadIdx.x & 63;
    int beg = row_ptr[node], end = row_ptr[node + 1];

    float sum = 0.f;
    for (int i = beg + (lane >> 2); i < end; i += 16)
        sum += bf2f(w_edge[i * 4 + (lane & 3)]);
#pragma unroll
    for (int m = 4; m < 64; m <<= 1) sum += __shfl_xor(sum, m, 64);

    int hq = lane >> 4;
    float sh = __shfl(sum, hq, 64);
    float inv = 1.f / (sh + 1e-10f);

    float a0[8] = {0.f, 0.f, 0.f, 0.f, 0.f, 0.f, 0.f, 0.f};
    float a1[8] = {0.f, 0.f, 0.f, 0.f, 0.f, 0.f, 0.f, 0.f};
    int i = beg;
    for (; i + 7 < end; i += 8) {
#pragma unroll
        for (int k = 0; k < 8; k++) {
            int s = col_src[i + k];
            float w = bf2f(w_edge[(i + k) * 4 + hq]);
            u32 hv = *(const u32*)&h[(size_t)s * 128 + lane * 2];
            a0[k] += w * bf2f(hv & 0xffff);
            a1[k] += w * bf2f(hv >> 16);
        }
    }
    for (; i < end; i++) {
        int s = col_src[i];
        float w = bf2f(w_edge[i * 4 + hq]);
        u32 hv = *(const u32*)&h[(size_t)s * 128 + lane * 2];
        a0[0] += w * bf2f(hv & 0xffff);
        a1[0] += w * bf2f(hv >> 16);
    }
    float acc0 = (((a0[0] + a0[1]) + (a0[2] + a0[3])) + ((a0[4] + a0[5]) + (a0[6] + a0[7]))) * inv;
    float acc1 = (((a1[0] + a1[1]) + (a1[2] + a1[3])) + ((a1[4] + a1[5]) + (a1[6] + a1[7]))) * inv;

    float r0, r1;
    if (XF32) {
        const float* x = (const float*)xin;
        float2 xv = *(const float2*)&x[(size_t)node * 128 + lane * 2];
        r0 = xv.x;
        r1 = xv.y;
    } else {
        const u16* x = (const u16*)xin;
        u32 xv = *(const u32*)&x[(size_t)node * 128 + lane * 2];
        r0 = bf2f(xv & 0xffff);
        r1 = bf2f(xv >> 16);
    }
    float o0 = ((acc0 > 0.f) ? acc0 : (__expf(acc0) - 1.f)) + r0;
    float o1 = ((acc1 > 0.f) ? acc1 : (__expf(acc1) - 1.f)) + r1;
    xout[(size_t)node * 128 + lane * 2]     = f2bf(o0);
    xout[(size_t)node * 128 + lane * 2 + 1] = f2bf(o1);
}

// ---------------- link predictor ----------------
__global__ void k_pair(const int* __restrict__ psrc, const int* __restrict__ pdst,
                       const u16* __restrict__ u, const u16* __restrict__ v,
                       const float* __restrict__ b1, const float* __restrict__ w2,
                       const float* __restrict__ b2, float* __restrict__ out) {
    int p = blockIdx.x * 4 + (threadIdx.x >> 6);
    int lane = threadIdx.x & 63;
    int s = psrc[p], d = pdst[p];
    float h0 = bf2f(u[(size_t)s * 128 + lane * 2])     + bf2f(v[(size_t)d * 128 + lane * 2])     + b1[lane * 2];
    float h1 = bf2f(u[(size_t)s * 128 + lane * 2 + 1]) + bf2f(v[(size_t)d * 128 + lane * 2 + 1]) + b1[lane * 2 + 1];
    h0 = (h0 > 0.f) ? h0 : 0.f;
    h1 = (h1 > 0.f) ? h1 : 0.f;
    float acc = h0 * w2[lane * 2] + h1 * w2[lane * 2 + 1];
#pragma unroll
    for (int m = 1; m < 64; m <<= 1) acc += __shfl_xor(acc, m, 64);
    if (lane == 0) out[p] = acc + b2[0];
}

extern "C" void kernel_launch(void* const* d_in, const int* in_sizes, int n_in,
                              void* d_out, int out_size, void* d_ws, size_t ws_size,
                              hipStream_t stream) {
    const float* embed  = (const float*)d_in[0];
    const float* W1     = (const float*)d_in[1];
    const float* a_src1 = (const float*)d_in[2];
    const float* a_dst1 = (const float*)d_in[3];
    const float* W2     = (const float*)d_in[4];
    const float* a_src2 = (const float*)d_in[5];
    const float* a_dst2 = (const float*)d_in[6];
    const float* lp_w1  = (const float*)d_in[7];
    const float* lp_b1  = (const float*)d_in[8];
    const float* lp_w2  = (const float*)d_in[9];
    const float* lp_b2  = (const float*)d_in[10];
    const int*   edge   = (const int*)d_in[11];
    const int*   lsrc   = (const int*)d_in[12];
    const int*   ldst   = (const int*)d_in[13];
    float* out = (float*)d_out;

    char* ws = (char*)d_ws;
    size_t off = 0;
    auto alloc = [&](size_t bytes) -> char* {
        char* p = ws + off;
        off += (bytes + 255) & ~(size_t)255;
        return p;
    };
    int*  row_ptr    = (int*)alloc((N_NODES + 1) * 4);
    int*  bucket_cur = (int*)alloc(NBUCKP * 4);
    int*  bstart     = (int*)alloc(NBUCKP * 4);
    int*  bfill      = (int*)alloc(NBUCKP * 4);
    int2* binned     = (int2*)alloc((size_t)NBUCKP * BUCK_CAP * 8);
    int2* col_sd     = (int2*)alloc((size_t)N_EDGES * 8);
    int*  col_src    = (int*)alloc((size_t)N_EDGES * 4);
    u16*  h          = (u16*)alloc((size_t)N_NODES * 128 * 2);
    float* al_s      = (float*)alloc((size_t)N_NODES * 4 * 4);
    float* al_d      = (float*)alloc((size_t)N_NODES * 4 * 4);
    u16*  x1         = (u16*)alloc((size_t)N_NODES * 128 * 2);
    u16*  z          = (u16*)alloc((size_t)N_NODES * 128 * 2);
    u16*  w_edge     = (u16*)alloc((size_t)N_EDGES * 4 * 2);
    u16*  Bf1        = (u16*)alloc(128 * 128 * 2);
    u16*  Bf2        = (u16*)alloc(128 * 128 * 2);
    u16*  BfA        = (u16*)alloc(128 * 128 * 2);
    u16*  BfB        = (u16*)alloc(128 * 128 * 2);
    u16* uu = h;    // reuse: h dead after layer-2 aggregation
    u16* vv = x1;   // reuse: x1 dead after layer-2 aggregation

    const int* esrc = edge;
    const int* edst = edge + N_EDGES;
    const int GB = (N_NODES + 63) / 64;

    k_prepB4<<<32, 256, 0, stream>>>(W1, W2, lp_w1, lp_w1 + 128 * 128, Bf1, Bf2, BfA, BfB);

    k_binit<<<1, NBUCKP, 0, stream>>>(bucket_cur);
    k_bin  <<<BIN_GRID, 256, 0, stream>>>(esrc, edst, bucket_cur, binned);
    k_bscan<<<1, NBUCKP, 0, stream>>>(bucket_cur, bstart, bfill);
    k_sort <<<NB_USED, 512, 0, stream>>>(binned, bstart, bfill, row_ptr, col_sd, col_src);

    // layer 1: h = embed @ W1 (+ fused alpha)
    k_gemm<true, false, true><<<GB, 256, 0, stream>>>(embed, Bf1, nullptr, h, nullptr,
                                                      a_src1, a_dst1, al_s, al_d, N_NODES);
    k_score<<<N_EDGES * 4 / 256, 256, 0, stream>>>(col_sd, al_s, al_d, w_edge);
    k_agg<true><<<N_NODES / 4, 256, 0, stream>>>(row_ptr, col_src, w_edge, h, embed, x1);
    // layer 2: h = x1 @ W2 (+ fused alpha)
    k_gemm<false, false, true><<<GB, 256, 0, stream>>>(x1, Bf2, nullptr, h, nullptr,
                                                       a_src2, a_dst2, al_s, al_d, N_NODES);
    k_score<<<N_EDGES * 4 / 256, 256, 0, stream>>>(col_sd, al_s, al_d, w_edge);
    k_agg<false><<<N_NODES / 4, 256, 0, stream>>>(row_ptr, col_src, w_edge, h, x1, z);
    // link predictor
    k_gemm<false, true, false><<<GB, 256, 0, stream>>>(z, BfA, BfB, uu, vv,
                                                       nullptr, nullptr, nullptr, nullptr, N_NODES);
    k_pair<<<N_PAIRS / 4, 256, 0, stream>>>(lsrc, ldst, uu, vv, lp_b1, lp_w2, lp_b2, out);
}

// Round 10
// 454.213 us; speedup vs baseline: 1.0721x; 1.0104x over previous
//
#include <hip/hip_runtime.h>

typedef unsigned short u16;
typedef unsigned int u32;
typedef __attribute__((ext_vector_type(8))) short short8;
typedef __attribute__((ext_vector_type(4))) float float4v;

#define N_NODES 100000
#define N_EDGES 1600000
#define N_PAIRS 100000
#define NBUCKP 256
#define NB_USED 196
#define BUCK_CAP 8704
#define BIN_GRID 391

__device__ __forceinline__ float bf2f(u32 lo16) {
    union { u32 u; float f; } v;
    v.u = lo16 << 16;
    return v.f;
}
__device__ __forceinline__ u16 f2bf(float f) {
    union { float f; u32 u; } v;
    v.f = f;
    u32 r = v.u + 0x7fffu + ((v.u >> 16) & 1u);
    return (u16)(r >> 16);
}

// ---------------- pre-swizzle weights + init bucket cursors (block 32) ----------------
__global__ __launch_bounds__(256) void k_prepB4(const float* __restrict__ W1, const float* __restrict__ W2,
                                                const float* __restrict__ WA, const float* __restrict__ WB,
                                                u16* __restrict__ B1, u16* __restrict__ B2,
                                                u16* __restrict__ BA, u16* __restrict__ BB,
                                                int* __restrict__ bucket_cur) {
    if (blockIdx.x == 32) {
        bucket_cur[threadIdx.x] = threadIdx.x * BUCK_CAP;
        return;
    }
    int w = blockIdx.x >> 3;
    const float* W = (w == 0) ? W1 : (w == 1) ? W2 : (w == 2) ? WA : WB;
    u16* Bf = (w == 0) ? B1 : (w == 1) ? B2 : (w == 2) ? BA : BB;
    int t = (blockIdx.x & 7) * 256 + threadIdx.x;
    int kk = t >> 9, tn = (t >> 6) & 7, quad = (t >> 4) & 3, l15 = t & 15;
#pragma unroll
    for (int j = 0; j < 8; j++) {
        int k = kk * 32 + quad * 8 + j;
        int n = tn * 16 + l15;
        Bf[(size_t)t * 8 + j] = f2bf(W[k * 128 + n]);
    }
}

// ---------------- bin edges into padded buckets ----------------
__global__ __launch_bounds__(256) void k_bin(const int* __restrict__ esrc, const int* __restrict__ edst,
                                             int* bucket_cur, int2* __restrict__ binned) {
    __shared__ int cnt[NBUCKP];
    __shared__ int base[NBUCKP];
    int t = threadIdx.x;
    cnt[t] = 0;
    __syncthreads();
    int s[16], d[16], r[16];
    int e0 = blockIdx.x * 4096;
#pragma unroll
    for (int k = 0; k < 16; k++) {
        int e = e0 + k * 256 + t;
        if (e < N_EDGES) {
            s[k] = esrc[e];
            d[k] = edst[e];
            r[k] = atomicAdd(&cnt[d[k] >> 9], 1);
        } else {
            d[k] = -1;
        }
    }
    __syncthreads();
    base[t] = cnt[t] ? atomicAdd(&bucket_cur[t], cnt[t]) : 0;
    __syncthreads();
#pragma unroll
    for (int k = 0; k < 16; k++) {
        if (d[k] >= 0) {
            int bk = d[k] >> 9;
            int pos = base[bk] + r[k];
            if (pos < (bk + 1) * BUCK_CAP)
                binned[pos] = make_int2(s[k], d[k]);
        }
    }
}

// ---------------- per-bucket LDS counting sort (bucket-base scan inlined) ----------------
__global__ __launch_bounds__(512) void k_sort(const int2* __restrict__ binned,
                                              const int* __restrict__ bucket_cur,
                                              int* __restrict__ row_ptr,
                                              int2* __restrict__ col_sd,
                                              int* __restrict__ col_src) {
    __shared__ int cnt[512];
    __shared__ int sm[512];
    int b = blockIdx.x, t = threadIdx.x;

    // base = sum of fills of buckets < b (redundant per block)
    int partial = 0;
    if (t < b) partial = bucket_cur[t] - t * BUCK_CAP;   // b <= 195 < 512: one element per thread
    sm[t] = partial;
    __syncthreads();
    for (int o = 256; o >= 1; o >>= 1) {
        if (t < o) sm[t] += sm[t + o];
        __syncthreads();
    }
    int base = sm[0];
    int n_e = bucket_cur[b] - b * BUCK_CAP;
    if (n_e > BUCK_CAP) n_e = BUCK_CAP;
    __syncthreads();

    cnt[t] = 0;
    __syncthreads();
    const int2* ebase = binned + (size_t)b * BUCK_CAP;
    for (int i = t; i < n_e; i += 512)
        atomicAdd(&cnt[ebase[i].y & 511], 1);
    __syncthreads();
    int v = cnt[t];
    sm[t] = v;
    __syncthreads();
    for (int o = 1; o < 512; o <<= 1) {
        int x = (t >= o) ? sm[t - o] : 0;
        __syncthreads();
        sm[t] += x;
        __syncthreads();
    }
    int excl = base + sm[t] - v;
    int node = b * 512 + t;
    if (node <= N_NODES) row_ptr[node] = excl;
    cnt[t] = excl;
    __syncthreads();
    for (int i = t; i < n_e; i += 512) {
        int2 sd = ebase[i];
        int p = atomicAdd(&cnt[sd.y & 511], 1);
        col_sd[p] = sd;
        col_src[p] = sd.x;
    }
}

// ---------------- MFMA GEMM ----------------
// QUANT: C -> int8 row-quantized hq + per-row f32 scale sc, plus fused alpha epilogue.
// !QUANT: C (bf16), optional DUAL second output.
template<bool AF32, bool DUAL, bool QUANT>
__global__ __launch_bounds__(256) void k_gemm(const void* __restrict__ Ap,
                                              const u16* __restrict__ Bf,
                                              const u16* __restrict__ Bf2,
                                              u16* __restrict__ C,
                                              u16* __restrict__ C2,
                                              char* __restrict__ hq,
                                              float* __restrict__ sc,
                                              const float* __restrict__ a_src,
                                              const float* __restrict__ a_dst,
                                              float* __restrict__ al_s,
                                              float* __restrict__ al_d, int M) {
    int wave = threadIdx.x >> 6, lane = threadIdx.x & 63;
    int quad = lane >> 4, l15 = lane & 15;
    int row0 = blockIdx.x * 64 + wave * 16;
    int m = row0 + l15;
    int mload = (m < M) ? m : (M - 1);

    short8 a[4];
    if (AF32) {
        const float* A = (const float*)Ap;
#pragma unroll
        for (int kk = 0; kk < 4; kk++) {
            const float* p = A + (size_t)mload * 128 + kk * 32 + quad * 8;
            float4 f0 = *(const float4*)p;
            float4 f1 = *(const float4*)(p + 4);
            short8 av;
            av[0] = (short)f2bf(f0.x); av[1] = (short)f2bf(f0.y);
            av[2] = (short)f2bf(f0.z); av[3] = (short)f2bf(f0.w);
            av[4] = (short)f2bf(f1.x); av[5] = (short)f2bf(f1.y);
            av[6] = (short)f2bf(f1.z); av[7] = (short)f2bf(f1.w);
            a[kk] = av;
        }
    } else {
        const u16* A = (const u16*)Ap;
#pragma unroll
        for (int kk = 0; kk < 4; kk++)
            a[kk] = *(const short8*)(A + (size_t)mload * 128 + kk * 32 + quad * 8);
    }

    float4v acc[8], acc2[8];
#pragma unroll
    for (int tn = 0; tn < 8; tn++) {
        acc[tn] = (float4v){0.f, 0.f, 0.f, 0.f};
        if (DUAL) acc2[tn] = (float4v){0.f, 0.f, 0.f, 0.f};
    }

#pragma unroll
    for (int kk = 0; kk < 4; kk++) {
#pragma unroll
        for (int tn = 0; tn < 8; tn++) {
            short8 b = *(const short8*)(Bf + ((size_t)((kk * 8 + tn) * 64 + lane)) * 8);
            acc[tn] = __builtin_amdgcn_mfma_f32_16x16x32_bf16(a[kk], b, acc[tn], 0, 0, 0);
            if (DUAL) {
                short8 b2 = *(const short8*)(Bf2 + ((size_t)((kk * 8 + tn) * 64 + lane)) * 8);
                acc2[tn] = __builtin_amdgcn_mfma_f32_16x16x32_bf16(a[kk], b2, acc2[tn], 0, 0, 0);
            }
        }
    }

    float as0[4], as1[4], ad0[4], ad1[4];
    if (QUANT) {
#pragma unroll
        for (int hd = 0; hd < 4; hd++) {
            as0[hd] = a_src[hd * 32 + l15];
            as1[hd] = a_src[hd * 32 + 16 + l15];
            ad0[hd] = a_dst[hd * 32 + l15];
            ad1[hd] = a_dst[hd * 32 + 16 + l15];
        }
    }

#pragma unroll
    for (int rg = 0; rg < 4; rg++) {
        int gr = row0 + quad * 4 + rg;
        bool ok = (gr < M);
        if (!QUANT) {
            if (ok) {
#pragma unroll
                for (int tn = 0; tn < 8; tn++) {
                    C[(size_t)gr * 128 + tn * 16 + l15] = f2bf(acc[tn][rg]);
                    if (DUAL) C2[(size_t)gr * 128 + tn * 16 + l15] = f2bf(acc2[tn][rg]);
                }
            }
        } else {
            // row amax over all 128 cols (8 local + 16-lane butterfly)
            float amax = 0.f;
#pragma unroll
            for (int tn = 0; tn < 8; tn++) amax = fmaxf(amax, fabsf(acc[tn][rg]));
#pragma unroll
            for (int mm = 1; mm < 16; mm <<= 1) amax = fmaxf(amax, __shfl_xor(amax, mm, 64));
            float inv_s = (amax > 0.f) ? 127.f / amax : 0.f;
            if (ok) {
#pragma unroll
                for (int tn = 0; tn < 8; tn++) {
                    int q = (int)rintf(acc[tn][rg] * inv_s);
                    hq[(size_t)gr * 128 + tn * 16 + l15] = (char)q;
                }
                if (l15 == 0) sc[gr] = amax * (1.f / 127.f);
            }
            // fused alpha
            float ps[4], pd[4];
#pragma unroll
            for (int hd = 0; hd < 4; hd++) {
                float c0 = acc[2 * hd][rg];
                float c1 = acc[2 * hd + 1][rg];
                ps[hd] = c0 * as0[hd] + c1 * as1[hd];
                pd[hd] = c0 * ad0[hd] + c1 * ad1[hd];
            }
#pragma unroll
            for (int mm = 1; mm < 16; mm <<= 1) {
#pragma unroll
                for (int hd = 0; hd < 4; hd++) {
                    ps[hd] += __shfl_xor(ps[hd], mm, 64);
                    pd[hd] += __shfl_xor(pd[hd], mm, 64);
                }
            }
            if (ok && l15 < 4) {
                float vs = (l15 == 0) ? ps[0] : (l15 == 1) ? ps[1] : (l15 == 2) ? ps[2] : ps[3];
                float vd = (l15 == 0) ? pd[0] : (l15 == 1) ? pd[1] : (l15 == 2) ? pd[2] : pd[3];
                al_s[gr * 4 + l15] = vs;
                al_d[gr * 4 + l15] = vd;
            }
        }
    }
}

// ---------------- edge-parallel scores (bf16) ----------------
__global__ void k_score(const int2* __restrict__ col_sd,
                        const float* __restrict__ al_s, const float* __restrict__ al_d,
                        u16* __restrict__ w_edge) {
    int g = blockIdx.x * 256 + threadIdx.x;  // [0, 4E)
    int i = g >> 2, hd = g & 3;
    int2 sd = col_sd[i];
    float e = al_s[sd.x * 4 + hd] + al_d[sd.y * 4 + hd];
    e = (e >= 0.f) ? e : 0.2f * e;
    w_edge[g] = f2bf(__expf(e));
}

// ---------------- aggregation: sum pass + int8 weighted gather (scale folded into w) ----------------
template<bool XF32>
__global__ void k_agg(const int* __restrict__ row_ptr, const int* __restrict__ col_src,
                      const u16* __restrict__ w_edge,
                      const char* __restrict__ hq, const float* __restrict__ sc,
                      const void* __restrict__ xin, u16* __restrict__ xout) {
    int node = blockIdx.x * 4 + (threadIdx.x >> 6);
    int lane = threadIdx.x & 63;
    int beg = row_ptr[node], end = row_ptr[node + 1];

    float sum = 0.f;
    for (int i = beg + (lane >> 2); i < end; i += 16)
        sum += bf2f(w_edge[i * 4 + (lane & 3)]);
#pragma unroll
    for (int m = 4; m < 64; m <<= 1) sum += __shfl_xor(sum, m, 64);

    int hh = lane >> 4;
    float sh = __shfl(sum, hh, 64);
    float inv = 1.f / (sh + 1e-10f);

    float a0[4] = {0.f, 0.f, 0.f, 0.f};
    float a1[4] = {0.f, 0.f, 0.f, 0.f};
    int i = beg;
    for (; i + 3 < end; i += 4) {
#pragma unroll
        for (int k = 0; k < 4; k++) {
            int s = col_src[i + k];
            float w = bf2f(w_edge[(i + k) * 4 + hh]) * sc[s];
            u32 hv = *(const u16*)(hq + (size_t)s * 128 + lane * 2);
            a0[k] += w * (float)(int)(signed char)(hv & 0xFF);
            a1[k] += w * (float)(int)(signed char)(hv >> 8);
        }
    }
    for (; i < end; i++) {
        int s = col_src[i];
        float w = bf2f(w_edge[i * 4 + hh]) * sc[s];
        u32 hv = *(const u16*)(hq + (size_t)s * 128 + lane * 2);
        a0[0] += w * (float)(int)(signed char)(hv & 0xFF);
        a1[0] += w * (float)(int)(signed char)(hv >> 8);
    }
    float acc0 = ((a0[0] + a0[1]) + (a0[2] + a0[3])) * inv;
    float acc1 = ((a1[0] + a1[1]) + (a1[2] + a1[3])) * inv;

    float r0, r1;
    if (XF32) {
        const float* x = (const float*)xin;
        float2 xv = *(const float2*)&x[(size_t)node * 128 + lane * 2];
        r0 = xv.x;
        r1 = xv.y;
    } else {
        const u16* x = (const u16*)xin;
        u32 xv = *(const u32*)&x[(size_t)node * 128 + lane * 2];
        r0 = bf2f(xv & 0xffff);
        r1 = bf2f(xv >> 16);
    }
    float o0 = ((acc0 > 0.f) ? acc0 : (__expf(acc0) - 1.f)) + r0;
    float o1 = ((acc1 > 0.f) ? acc1 : (__expf(acc1) - 1.f)) + r1;
    xout[(size_t)node * 128 + lane * 2]     = f2bf(o0);
    xout[(size_t)node * 128 + lane * 2 + 1] = f2bf(o1);
}

// ---------------- link predictor ----------------
__global__ void k_pair(const int* __restrict__ psrc, const int* __restrict__ pdst,
                       const u16* __restrict__ u, const u16* __restrict__ v,
                       const float* __restrict__ b1, const float* __restrict__ w2,
                       const float* __restrict__ b2, float* __restrict__ out) {
    int p = blockIdx.x * 4 + (threadIdx.x >> 6);
    int lane = threadIdx.x & 63;
    int s = psrc[p], d = pdst[p];
    float h0 = bf2f(u[(size_t)s * 128 + lane * 2])     + bf2f(v[(size_t)d * 128 + lane * 2])     + b1[lane * 2];
    float h1 = bf2f(u[(size_t)s * 128 + lane * 2 + 1]) + bf2f(v[(size_t)d * 128 + lane * 2 + 1]) + b1[lane * 2 + 1];
    h0 = (h0 > 0.f) ? h0 : 0.f;
    h1 = (h1 > 0.f) ? h1 : 0.f;
    float acc = h0 * w2[lane * 2] + h1 * w2[lane * 2 + 1];
#pragma unroll
    for (int m = 1; m < 64; m <<= 1) acc += __shfl_xor(acc, m, 64);
    if (lane == 0) out[p] = acc + b2[0];
}

extern "C" void kernel_launch(void* const* d_in, const int* in_sizes, int n_in,
                              void* d_out, int out_size, void* d_ws, size_t ws_size,
                              hipStream_t stream) {
    const float* embed  = (const float*)d_in[0];
    const float* W1     = (const float*)d_in[1];
    const float* a_src1 = (const float*)d_in[2];
    const float* a_dst1 = (const float*)d_in[3];
    const float* W2     = (const float*)d_in[4];
    const float* a_src2 = (const float*)d_in[5];
    const float* a_dst2 = (const float*)d_in[6];
    const float* lp_w1  = (const float*)d_in[7];
    const float* lp_b1  = (const float*)d_in[8];
    const float* lp_w2  = (const float*)d_in[9];
    const float* lp_b2  = (const float*)d_in[10];
    const int*   edge   = (const int*)d_in[11];
    const int*   lsrc   = (const int*)d_in[12];
    const int*   ldst   = (const int*)d_in[13];
    float* out = (float*)d_out;

    char* ws = (char*)d_ws;
    size_t off = 0;
    auto alloc = [&](size_t bytes) -> char* {
        char* p = ws + off;
        off += (bytes + 255) & ~(size_t)255;
        return p;
    };
    int*  row_ptr    = (int*)alloc((N_NODES + 1) * 4);
    int*  bucket_cur = (int*)alloc(NBUCKP * 4);
    int2* binned     = (int2*)alloc((size_t)NBUCKP * BUCK_CAP * 8);
    int2* col_sd     = (int2*)alloc((size_t)N_EDGES * 8);
    int*  col_src    = (int*)alloc((size_t)N_EDGES * 4);
    char* hq         = (char*)alloc((size_t)N_NODES * 128);
    float* sc        = (float*)alloc((size_t)N_NODES * 4);
    float* al_s      = (float*)alloc((size_t)N_NODES * 4 * 4);
    float* al_d      = (float*)alloc((size_t)N_NODES * 4 * 4);
    u16*  x1         = (u16*)alloc((size_t)N_NODES * 128 * 2);
    u16*  z          = (u16*)alloc((size_t)N_NODES * 128 * 2);
    u16*  uu         = (u16*)alloc((size_t)N_NODES * 128 * 2);
    u16*  vv         = (u16*)alloc((size_t)N_NODES * 128 * 2);
    u16*  w_edge     = (u16*)alloc((size_t)N_EDGES * 4 * 2);
    u16*  Bf1        = (u16*)alloc(128 * 128 * 2);
    u16*  Bf2        = (u16*)alloc(128 * 128 * 2);
    u16*  BfA        = (u16*)alloc(128 * 128 * 2);
    u16*  BfB        = (u16*)alloc(128 * 128 * 2);

    const int* esrc = edge;
    const int* edst = edge + N_EDGES;
    const int GB = (N_NODES + 63) / 64;

    // weights + bucket_cur init (block 32)
    k_prepB4<<<33, 256, 0, stream>>>(W1, W2, lp_w1, lp_w1 + 128 * 128, Bf1, Bf2, BfA, BfB, bucket_cur);

    k_bin <<<BIN_GRID, 256, 0, stream>>>(esrc, edst, bucket_cur, binned);
    k_sort<<<NB_USED, 512, 0, stream>>>(binned, bucket_cur, row_ptr, col_sd, col_src);

    // layer 1: hq = int8(embed @ W1), fused alpha
    k_gemm<true, false, true><<<GB, 256, 0, stream>>>(embed, Bf1, nullptr, nullptr, nullptr,
                                                      hq, sc, a_src1, a_dst1, al_s, al_d, N_NODES);
    k_score<<<N_EDGES * 4 / 256, 256, 0, stream>>>(col_sd, al_s, al_d, w_edge);
    k_agg<true><<<N_NODES / 4, 256, 0, stream>>>(row_ptr, col_src, w_edge, hq, sc, embed, x1);
    // layer 2
    k_gemm<false, false, true><<<GB, 256, 0, stream>>>(x1, Bf2, nullptr, nullptr, nullptr,
                                                       hq, sc, a_src2, a_dst2, al_s, al_d, N_NODES);
    k_score<<<N_EDGES * 4 / 256, 256, 0, stream>>>(col_sd, al_s, al_d, w_edge);
    k_agg<false><<<N_NODES / 4, 256, 0, stream>>>(row_ptr, col_src, w_edge, hq, sc, x1, z);
    // link predictor
    k_gemm<false, true, false><<<GB, 256, 0, stream>>>(z, BfA, BfB, uu, vv,
                                                       nullptr, nullptr, nullptr, nullptr, nullptr, nullptr, N_NODES);
    k_pair<<<N_PAIRS / 4, 256, 0, stream>>>(lsrc, ldst, uu, vv, lp_b1, lp_w2, lp_b2, out);
}

// Round 11
// 442.714 us; speedup vs baseline: 1.0999x; 1.0260x over previous
//
#include <hip/hip_runtime.h>

typedef unsigned short u16;
typedef unsigned int u32;
typedef __attribute__((ext_vector_type(8))) short short8;
typedef __attribute__((ext_vector_type(4))) float float4v;

#define N_NODES 100000
#define N_EDGES 1600000
#define N_PAIRS 100000
#define NBUCKP 256
#define NB_USED 196
#define BUCK_CAP 8704
#define BIN_GRID 391

__device__ __forceinline__ float bf2f(u32 lo16) {
    union { u32 u; float f; } v;
    v.u = lo16 << 16;
    return v.f;
}
__device__ __forceinline__ u16 f2bf(float f) {
    union { float f; u32 u; } v;
    v.f = f;
    u32 r = v.u + 0x7fffu + ((v.u >> 16) & 1u);
    return (u16)(r >> 16);
}

// ---------------- pre-swizzle weights + init bucket cursors (block 32) ----------------
__global__ __launch_bounds__(256) void k_prepB4(const float* __restrict__ W1, const float* __restrict__ W2,
                                                const float* __restrict__ WA, const float* __restrict__ WB,
                                                u16* __restrict__ B1, u16* __restrict__ B2,
                                                u16* __restrict__ BA, u16* __restrict__ BB,
                                                int* __restrict__ bucket_cur) {
    if (blockIdx.x == 32) {
        bucket_cur[threadIdx.x] = threadIdx.x * BUCK_CAP;
        return;
    }
    int w = blockIdx.x >> 3;
    const float* W = (w == 0) ? W1 : (w == 1) ? W2 : (w == 2) ? WA : WB;
    u16* Bf = (w == 0) ? B1 : (w == 1) ? B2 : (w == 2) ? BA : BB;
    int t = (blockIdx.x & 7) * 256 + threadIdx.x;
    int kk = t >> 9, tn = (t >> 6) & 7, quad = (t >> 4) & 3, l15 = t & 15;
#pragma unroll
    for (int j = 0; j < 8; j++) {
        int k = kk * 32 + quad * 8 + j;
        int n = tn * 16 + l15;
        Bf[(size_t)t * 8 + j] = f2bf(W[k * 128 + n]);
    }
}

// ---------------- bin edges into padded buckets ----------------
__global__ __launch_bounds__(256) void k_bin(const int* __restrict__ esrc, const int* __restrict__ edst,
                                             int* bucket_cur, int2* __restrict__ binned) {
    __shared__ int cnt[NBUCKP];
    __shared__ int base[NBUCKP];
    int t = threadIdx.x;
    cnt[t] = 0;
    __syncthreads();
    int s[16], d[16], r[16];
    int e0 = blockIdx.x * 4096;
#pragma unroll
    for (int k = 0; k < 16; k++) {
        int e = e0 + k * 256 + t;
        if (e < N_EDGES) {
            s[k] = esrc[e];
            d[k] = edst[e];
            r[k] = atomicAdd(&cnt[d[k] >> 9], 1);
        } else {
            d[k] = -1;
        }
    }
    __syncthreads();
    base[t] = cnt[t] ? atomicAdd(&bucket_cur[t], cnt[t]) : 0;
    __syncthreads();
#pragma unroll
    for (int k = 0; k < 16; k++) {
        if (d[k] >= 0) {
            int bk = d[k] >> 9;
            int pos = base[bk] + r[k];
            if (pos < (bk + 1) * BUCK_CAP)
                binned[pos] = make_int2(s[k], d[k]);
        }
    }
}

// ---------------- per-bucket LDS counting sort (bucket-base scan inlined) ----------------
__global__ __launch_bounds__(512) void k_sort(const int2* __restrict__ binned,
                                              const int* __restrict__ bucket_cur,
                                              int* __restrict__ row_ptr,
                                              int2* __restrict__ col_sd,
                                              int* __restrict__ col_src) {
    __shared__ int cnt[512];
    __shared__ int sm[512];
    int b = blockIdx.x, t = threadIdx.x;

    int partial = 0;
    if (t < b) partial = bucket_cur[t] - t * BUCK_CAP;
    sm[t] = partial;
    __syncthreads();
    for (int o = 256; o >= 1; o >>= 1) {
        if (t < o) sm[t] += sm[t + o];
        __syncthreads();
    }
    int base = sm[0];
    int n_e = bucket_cur[b] - b * BUCK_CAP;
    if (n_e > BUCK_CAP) n_e = BUCK_CAP;
    __syncthreads();

    cnt[t] = 0;
    __syncthreads();
    const int2* ebase = binned + (size_t)b * BUCK_CAP;
    for (int i = t; i < n_e; i += 512)
        atomicAdd(&cnt[ebase[i].y & 511], 1);
    __syncthreads();
    int v = cnt[t];
    sm[t] = v;
    __syncthreads();
    for (int o = 1; o < 512; o <<= 1) {
        int x = (t >= o) ? sm[t - o] : 0;
        __syncthreads();
        sm[t] += x;
        __syncthreads();
    }
    int excl = base + sm[t] - v;
    int node = b * 512 + t;
    if (node <= N_NODES) row_ptr[node] = excl;
    cnt[t] = excl;
    __syncthreads();
    for (int i = t; i < n_e; i += 512) {
        int2 sd = ebase[i];
        int p = atomicAdd(&cnt[sd.y & 511], 1);
        col_sd[p] = sd;
        col_src[p] = sd.x;
    }
}

// ---------------- MFMA GEMM ----------------
template<bool AF32, bool DUAL, bool QUANT>
__global__ __launch_bounds__(256) void k_gemm(const void* __restrict__ Ap,
                                              const u16* __restrict__ Bf,
                                              const u16* __restrict__ Bf2,
                                              u16* __restrict__ C,
                                              u16* __restrict__ C2,
                                              char* __restrict__ hq,
                                              float* __restrict__ sc,
                                              const float* __restrict__ a_src,
                                              const float* __restrict__ a_dst,
                                              float* __restrict__ al_s,
                                              float* __restrict__ al_d, int M) {
    int wave = threadIdx.x >> 6, lane = threadIdx.x & 63;
    int quad = lane >> 4, l15 = lane & 15;
    int row0 = blockIdx.x * 64 + wave * 16;
    int m = row0 + l15;
    int mload = (m < M) ? m : (M - 1);

    short8 a[4];
    if (AF32) {
        const float* A = (const float*)Ap;
#pragma unroll
        for (int kk = 0; kk < 4; kk++) {
            const float* p = A + (size_t)mload * 128 + kk * 32 + quad * 8;
            float4 f0 = *(const float4*)p;
            float4 f1 = *(const float4*)(p + 4);
            short8 av;
            av[0] = (short)f2bf(f0.x); av[1] = (short)f2bf(f0.y);
            av[2] = (short)f2bf(f0.z); av[3] = (short)f2bf(f0.w);
            av[4] = (short)f2bf(f1.x); av[5] = (short)f2bf(f1.y);
            av[6] = (short)f2bf(f1.z); av[7] = (short)f2bf(f1.w);
            a[kk] = av;
        }
    } else {
        const u16* A = (const u16*)Ap;
#pragma unroll
        for (int kk = 0; kk < 4; kk++)
            a[kk] = *(const short8*)(A + (size_t)mload * 128 + kk * 32 + quad * 8);
    }

    float4v acc[8], acc2[8];
#pragma unroll
    for (int tn = 0; tn < 8; tn++) {
        acc[tn] = (float4v){0.f, 0.f, 0.f, 0.f};
        if (DUAL) acc2[tn] = (float4v){0.f, 0.f, 0.f, 0.f};
    }

#pragma unroll
    for (int kk = 0; kk < 4; kk++) {
#pragma unroll
        for (int tn = 0; tn < 8; tn++) {
            short8 b = *(const short8*)(Bf + ((size_t)((kk * 8 + tn) * 64 + lane)) * 8);
            acc[tn] = __builtin_amdgcn_mfma_f32_16x16x32_bf16(a[kk], b, acc[tn], 0, 0, 0);
            if (DUAL) {
                short8 b2 = *(const short8*)(Bf2 + ((size_t)((kk * 8 + tn) * 64 + lane)) * 8);
                acc2[tn] = __builtin_amdgcn_mfma_f32_16x16x32_bf16(a[kk], b2, acc2[tn], 0, 0, 0);
            }
        }
    }

    float as0[4], as1[4], ad0[4], ad1[4];
    if (QUANT) {
#pragma unroll
        for (int hd = 0; hd < 4; hd++) {
            as0[hd] = a_src[hd * 32 + l15];
            as1[hd] = a_src[hd * 32 + 16 + l15];
            ad0[hd] = a_dst[hd * 32 + l15];
            ad1[hd] = a_dst[hd * 32 + 16 + l15];
        }
    }

#pragma unroll
    for (int rg = 0; rg < 4; rg++) {
        int gr = row0 + quad * 4 + rg;
        bool ok = (gr < M);
        if (!QUANT) {
            if (ok) {
#pragma unroll
                for (int tn = 0; tn < 8; tn++) {
                    C[(size_t)gr * 128 + tn * 16 + l15] = f2bf(acc[tn][rg]);
                    if (DUAL) C2[(size_t)gr * 128 + tn * 16 + l15] = f2bf(acc2[tn][rg]);
                }
            }
        } else {
            float amax = 0.f;
#pragma unroll
            for (int tn = 0; tn < 8; tn++) amax = fmaxf(amax, fabsf(acc[tn][rg]));
#pragma unroll
            for (int mm = 1; mm < 16; mm <<= 1) amax = fmaxf(amax, __shfl_xor(amax, mm, 64));
            float inv_s = (amax > 0.f) ? 127.f / amax : 0.f;
            if (ok) {
#pragma unroll
                for (int tn = 0; tn < 8; tn++) {
                    int q = (int)rintf(acc[tn][rg] * inv_s);
                    hq[(size_t)gr * 128 + tn * 16 + l15] = (char)q;
                }
                if (l15 == 0) sc[gr] = amax * (1.f / 127.f);
            }
            float ps[4], pd[4];
#pragma unroll
            for (int hd = 0; hd < 4; hd++) {
                float c0 = acc[2 * hd][rg];
                float c1 = acc[2 * hd + 1][rg];
                ps[hd] = c0 * as0[hd] + c1 * as1[hd];
                pd[hd] = c0 * ad0[hd] + c1 * ad1[hd];
            }
#pragma unroll
            for (int mm = 1; mm < 16; mm <<= 1) {
#pragma unroll
                for (int hd = 0; hd < 4; hd++) {
                    ps[hd] += __shfl_xor(ps[hd], mm, 64);
                    pd[hd] += __shfl_xor(pd[hd], mm, 64);
                }
            }
            if (ok && l15 < 4) {
                float vs = (l15 == 0) ? ps[0] : (l15 == 1) ? ps[1] : (l15 == 2) ? ps[2] : ps[3];
                float vd = (l15 == 0) ? pd[0] : (l15 == 1) ? pd[1] : (l15 == 2) ? pd[2] : pd[3];
                al_s[gr * 4 + l15] = vs;
                al_d[gr * 4 + l15] = vd;
            }
        }
    }
}

// ---------------- edge-parallel scores: pack (bf16(w*sc[src])<<16 | bf16(w)) ----------------
__global__ void k_score(const int2* __restrict__ col_sd,
                        const float* __restrict__ al_s, const float* __restrict__ al_d,
                        const float* __restrict__ sc, u32* __restrict__ w_pack) {
    int g = blockIdx.x * 256 + threadIdx.x;  // [0, 4E)
    int i = g >> 2, hd = g & 3;
    int2 sd = col_sd[i];
    float e = al_s[sd.x * 4 + hd] + al_d[sd.y * 4 + hd];
    e = (e >= 0.f) ? e : 0.2f * e;
    float w = __expf(e);
    float wsc = w * sc[sd.x];
    w_pack[g] = ((u32)f2bf(wsc) << 16) | (u32)f2bf(w);
}

// ---------------- aggregation: single chunked pass, inline sum, int8 gather ----------------
template<bool XF32>
__global__ void k_agg(const int* __restrict__ row_ptr, const int* __restrict__ col_src,
                      const u32* __restrict__ w_pack,
                      const char* __restrict__ hq,
                      const void* __restrict__ xin, u16* __restrict__ xout) {
    int node = blockIdx.x * 4 + (threadIdx.x >> 6);
    int lane = threadIdx.x & 63;
    int beg = row_ptr[node], end = row_ptr[node + 1];
    int hh = lane >> 4;                       // this lane's head
    const char* hqp = hq + lane * 2;          // per-lane byte base

    float sumw = 0.f;
    float a0[2] = {0.f, 0.f};
    float a1[2] = {0.f, 0.f};

    int i = beg;
    // fast path: 8-edge chunks, 2 coalesced loads + static-unrolled broadcast
    for (; i + 8 <= end; i += 8) {
        int sv = col_src[i + (lane & 7)];
        u32 wvv = w_pack[i * 4 + (lane & 31)];
#pragma unroll
        for (int j = 0; j < 8; j++) {
            int s = __shfl(sv, j);
            u32 wp = __shfl(wvv, j * 4 + hh);
            union { u32 u; float f; } cw, cs;
            cw.u = wp << 16;           // low bf16 = w
            cs.u = wp & 0xffff0000u;   // high bf16 = w*sc
            sumw += cw.f;
            u32 hv = *(const u16*)(hqp + (size_t)s * 128);
            a0[j & 1] += cs.f * (float)(int)(signed char)(hv & 0xFF);
            a1[j & 1] += cs.f * (float)(int)(signed char)(hv >> 8);
        }
    }
    // tail
    for (; i < end; i++) {
        int s = col_src[i];
        u32 wp = w_pack[i * 4 + hh];
        union { u32 u; float f; } cw, cs;
        cw.u = wp << 16;
        cs.u = wp & 0xffff0000u;
        sumw += cw.f;
        u32 hv = *(const u16*)(hqp + (size_t)s * 128);
        a0[0] += cs.f * (float)(int)(signed char)(hv & 0xFF);
        a1[0] += cs.f * (float)(int)(signed char)(hv >> 8);
    }

    float inv = 1.f / (sumw + 1e-10f);   // identical across each 16-lane head group
    float acc0 = (a0[0] + a0[1]) * inv;
    float acc1 = (a1[0] + a1[1]) * inv;

    float r0, r1;
    if (XF32) {
        const float* x = (const float*)xin;
        float2 xv = *(const float2*)&x[(size_t)node * 128 + lane * 2];
        r0 = xv.x;
        r1 = xv.y;
    } else {
        const u16* x = (const u16*)xin;
        u32 xv = *(const u32*)&x[(size_t)node * 128 + lane * 2];
        r0 = bf2f(xv & 0xffff);
        r1 = bf2f(xv >> 16);
    }
    float o0 = ((acc0 > 0.f) ? acc0 : (__expf(acc0) - 1.f)) + r0;
    float o1 = ((acc1 > 0.f) ? acc1 : (__expf(acc1) - 1.f)) + r1;
    xout[(size_t)node * 128 + lane * 2]     = f2bf(o0);
    xout[(size_t)node * 128 + lane * 2 + 1] = f2bf(o1);
}

// ---------------- link predictor ----------------
__global__ void k_pair(const int* __restrict__ psrc, const int* __restrict__ pdst,
                       const u16* __restrict__ u, const u16* __restrict__ v,
                       const float* __restrict__ b1, const float* __restrict__ w2,
                       const float* __restrict__ b2, float* __restrict__ out) {
    int p = blockIdx.x * 4 + (threadIdx.x >> 6);
    int lane = threadIdx.x & 63;
    int s = psrc[p], d = pdst[p];
    float h0 = bf2f(u[(size_t)s * 128 + lane * 2])     + bf2f(v[(size_t)d * 128 + lane * 2])     + b1[lane * 2];
    float h1 = bf2f(u[(size_t)s * 128 + lane * 2 + 1]) + bf2f(v[(size_t)d * 128 + lane * 2 + 1]) + b1[lane * 2 + 1];
    h0 = (h0 > 0.f) ? h0 : 0.f;
    h1 = (h1 > 0.f) ? h1 : 0.f;
    float acc = h0 * w2[lane * 2] + h1 * w2[lane * 2 + 1];
#pragma unroll
    for (int m = 1; m < 64; m <<= 1) acc += __shfl_xor(acc, m, 64);
    if (lane == 0) out[p] = acc + b2[0];
}

extern "C" void kernel_launch(void* const* d_in, const int* in_sizes, int n_in,
                              void* d_out, int out_size, void* d_ws, size_t ws_size,
                              hipStream_t stream) {
    const float* embed  = (const float*)d_in[0];
    const float* W1     = (const float*)d_in[1];
    const float* a_src1 = (const float*)d_in[2];
    const float* a_dst1 = (const float*)d_in[3];
    const float* W2     = (const float*)d_in[4];
    const float* a_src2 = (const float*)d_in[5];
    const float* a_dst2 = (const float*)d_in[6];
    const float* lp_w1  = (const float*)d_in[7];
    const float* lp_b1  = (const float*)d_in[8];
    const float* lp_w2  = (const float*)d_in[9];
    const float* lp_b2  = (const float*)d_in[10];
    const int*   edge   = (const int*)d_in[11];
    const int*   lsrc   = (const int*)d_in[12];
    const int*   ldst   = (const int*)d_in[13];
    float* out = (float*)d_out;

    char* ws = (char*)d_ws;
    size_t off = 0;
    auto alloc = [&](size_t bytes) -> char* {
        char* p = ws + off;
        off += (bytes + 255) & ~(size_t)255;
        return p;
    };
    int*  row_ptr    = (int*)alloc((N_NODES + 1) * 4);
    int*  bucket_cur = (int*)alloc(NBUCKP * 4);
    int2* binned     = (int2*)alloc((size_t)NBUCKP * BUCK_CAP * 8);
    int2* col_sd     = (int2*)alloc((size_t)N_EDGES * 8);
    int*  col_src    = (int*)alloc((size_t)N_EDGES * 4);
    char* hq         = (char*)alloc((size_t)N_NODES * 128);
    float* sc        = (float*)alloc((size_t)N_NODES * 4);
    float* al_s      = (float*)alloc((size_t)N_NODES * 4 * 4);
    float* al_d      = (float*)alloc((size_t)N_NODES * 4 * 4);
    u16*  x1         = (u16*)alloc((size_t)N_NODES * 128 * 2);
    u16*  z          = (u16*)alloc((size_t)N_NODES * 128 * 2);
    u16*  uu         = (u16*)alloc((size_t)N_NODES * 128 * 2);
    u16*  vv         = (u16*)alloc((size_t)N_NODES * 128 * 2);
    u32*  w_pack     = (u32*)alloc((size_t)N_EDGES * 4 * 4);
    u16*  Bf1        = (u16*)alloc(128 * 128 * 2);
    u16*  Bf2        = (u16*)alloc(128 * 128 * 2);
    u16*  BfA        = (u16*)alloc(128 * 128 * 2);
    u16*  BfB        = (u16*)alloc(128 * 128 * 2);

    const int* esrc = edge;
    const int* edst = edge + N_EDGES;
    const int GB = (N_NODES + 63) / 64;

    k_prepB4<<<33, 256, 0, stream>>>(W1, W2, lp_w1, lp_w1 + 128 * 128, Bf1, Bf2, BfA, BfB, bucket_cur);

    k_bin <<<BIN_GRID, 256, 0, stream>>>(esrc, edst, bucket_cur, binned);
    k_sort<<<NB_USED, 512, 0, stream>>>(binned, bucket_cur, row_ptr, col_sd, col_src);

    // layer 1: hq = int8(embed @ W1), fused alpha
    k_gemm<true, false, true><<<GB, 256, 0, stream>>>(embed, Bf1, nullptr, nullptr, nullptr,
                                                      hq, sc, a_src1, a_dst1, al_s, al_d, N_NODES);
    k_score<<<N_EDGES * 4 / 256, 256, 0, stream>>>(col_sd, al_s, al_d, sc, w_pack);
    k_agg<true><<<N_NODES / 4, 256, 0, stream>>>(row_ptr, col_src, w_pack, hq, embed, x1);
    // layer 2
    k_gemm<false, false, true><<<GB, 256, 0, stream>>>(x1, Bf2, nullptr, nullptr, nullptr,
                                                       hq, sc, a_src2, a_dst2, al_s, al_d, N_NODES);
    k_score<<<N_EDGES * 4 / 256, 256, 0, stream>>>(col_sd, al_s, al_d, sc, w_pack);
    k_agg<false><<<N_NODES / 4, 256, 0, stream>>>(row_ptr, col_src, w_pack, hq, x1, z);
    // link predictor
    k_gemm<false, true, false><<<GB, 256, 0, stream>>>(z, BfA, BfB, uu, vv,
                                                       nullptr, nullptr, nullptr, nullptr, nullptr, nullptr, N_NODES);
    k_pair<<<N_PAIRS / 4, 256, 0, stream>>>(lsrc, ldst, uu, vv, lp_b1, lp_w2, lp_b2, out);
}

// Round 12
// 406.776 us; speedup vs baseline: 1.1971x; 1.0883x over previous
//
#include <hip/hip_runtime.h>

typedef unsigned short u16;
typedef unsigned int u32;
typedef __attribute__((ext_vector_type(8))) short short8;
typedef __attribute__((ext_vector_type(4))) float float4v;

#define N_NODES 100000
#define N_EDGES 1600000
#define N_PAIRS 100000
#define NBUCKP 256
#define NB_USED 196
#define BUCK_CAP 8704
#define BIN_GRID 391

__device__ __forceinline__ float bf2f(u32 lo16) {
    union { u32 u; float f; } v;
    v.u = lo16 << 16;
    return v.f;
}
__device__ __forceinline__ u16 f2bf(float f) {
    union { float f; u32 u; } v;
    v.f = f;
    u32 r = v.u + 0x7fffu + ((v.u >> 16) & 1u);
    return (u16)(r >> 16);
}

// ---------------- pre-swizzle weights + init bucket cursors (block 32) ----------------
__global__ __launch_bounds__(256) void k_prepB4(const float* __restrict__ W1, const float* __restrict__ W2,
                                                const float* __restrict__ WA, const float* __restrict__ WB,
                                                u16* __restrict__ B1, u16* __restrict__ B2,
                                                u16* __restrict__ BA, u16* __restrict__ BB,
                                                int* __restrict__ bucket_cur) {
    if (blockIdx.x == 32) {
        bucket_cur[threadIdx.x] = threadIdx.x * BUCK_CAP;
        return;
    }
    int w = blockIdx.x >> 3;
    const float* W = (w == 0) ? W1 : (w == 1) ? W2 : (w == 2) ? WA : WB;
    u16* Bf = (w == 0) ? B1 : (w == 1) ? B2 : (w == 2) ? BA : BB;
    int t = (blockIdx.x & 7) * 256 + threadIdx.x;
    int kk = t >> 9, tn = (t >> 6) & 7, quad = (t >> 4) & 3, l15 = t & 15;
#pragma unroll
    for (int j = 0; j < 8; j++) {
        int k = kk * 32 + quad * 8 + j;
        int n = tn * 16 + l15;
        Bf[(size_t)t * 8 + j] = f2bf(W[k * 128 + n]);
    }
}

// ---------------- bin edges into padded buckets ----------------
__global__ __launch_bounds__(256) void k_bin(const int* __restrict__ esrc, const int* __restrict__ edst,
                                             int* bucket_cur, int2* __restrict__ binned) {
    __shared__ int cnt[NBUCKP];
    __shared__ int base[NBUCKP];
    int t = threadIdx.x;
    cnt[t] = 0;
    __syncthreads();
    int s[16], d[16], r[16];
    int e0 = blockIdx.x * 4096;
#pragma unroll
    for (int k = 0; k < 16; k++) {
        int e = e0 + k * 256 + t;
        if (e < N_EDGES) {
            s[k] = esrc[e];
            d[k] = edst[e];
            r[k] = atomicAdd(&cnt[d[k] >> 9], 1);
        } else {
            d[k] = -1;
        }
    }
    __syncthreads();
    base[t] = cnt[t] ? atomicAdd(&bucket_cur[t], cnt[t]) : 0;
    __syncthreads();
#pragma unroll
    for (int k = 0; k < 16; k++) {
        if (d[k] >= 0) {
            int bk = d[k] >> 9;
            int pos = base[bk] + r[k];
            if (pos < (bk + 1) * BUCK_CAP)
                binned[pos] = make_int2(s[k], d[k]);
        }
    }
}

// ---------------- per-bucket LDS counting sort -> row_ptr + col_src ----------------
__global__ __launch_bounds__(512) void k_sort(const int2* __restrict__ binned,
                                              const int* __restrict__ bucket_cur,
                                              int* __restrict__ row_ptr,
                                              int* __restrict__ col_src) {
    __shared__ int cnt[512];
    __shared__ int sm[512];
    int b = blockIdx.x, t = threadIdx.x;

    int partial = 0;
    if (t < b) partial = bucket_cur[t] - t * BUCK_CAP;
    sm[t] = partial;
    __syncthreads();
    for (int o = 256; o >= 1; o >>= 1) {
        if (t < o) sm[t] += sm[t + o];
        __syncthreads();
    }
    int base = sm[0];
    int n_e = bucket_cur[b] - b * BUCK_CAP;
    if (n_e > BUCK_CAP) n_e = BUCK_CAP;
    __syncthreads();

    cnt[t] = 0;
    __syncthreads();
    const int2* ebase = binned + (size_t)b * BUCK_CAP;
    for (int i = t; i < n_e; i += 512)
        atomicAdd(&cnt[ebase[i].y & 511], 1);
    __syncthreads();
    int v = cnt[t];
    sm[t] = v;
    __syncthreads();
    for (int o = 1; o < 512; o <<= 1) {
        int x = (t >= o) ? sm[t - o] : 0;
        __syncthreads();
        sm[t] += x;
        __syncthreads();
    }
    int excl = base + sm[t] - v;
    int node = b * 512 + t;
    if (node <= N_NODES) row_ptr[node] = excl;
    cnt[t] = excl;
    __syncthreads();
    for (int i = t; i < n_e; i += 512) {
        int2 sd = ebase[i];
        int p = atomicAdd(&cnt[sd.y & 511], 1);
        col_src[p] = sd.x;
    }
}

// ---------------- MFMA GEMM ----------------
// QUANT: int8 row-quantized hq + packed alsc[row] = {al_s[0..3], scale} + al_d.
template<bool AF32, bool DUAL, bool QUANT>
__global__ __launch_bounds__(256) void k_gemm(const void* __restrict__ Ap,
                                              const u16* __restrict__ Bf,
                                              const u16* __restrict__ Bf2,
                                              u16* __restrict__ C,
                                              u16* __restrict__ C2,
                                              char* __restrict__ hq,
                                              float* __restrict__ alsc,
                                              const float* __restrict__ a_src,
                                              const float* __restrict__ a_dst,
                                              float* __restrict__ al_d, int M) {
    int wave = threadIdx.x >> 6, lane = threadIdx.x & 63;
    int quad = lane >> 4, l15 = lane & 15;
    int row0 = blockIdx.x * 64 + wave * 16;
    int m = row0 + l15;
    int mload = (m < M) ? m : (M - 1);

    short8 a[4];
    if (AF32) {
        const float* A = (const float*)Ap;
#pragma unroll
        for (int kk = 0; kk < 4; kk++) {
            const float* p = A + (size_t)mload * 128 + kk * 32 + quad * 8;
            float4 f0 = *(const float4*)p;
            float4 f1 = *(const float4*)(p + 4);
            short8 av;
            av[0] = (short)f2bf(f0.x); av[1] = (short)f2bf(f0.y);
            av[2] = (short)f2bf(f0.z); av[3] = (short)f2bf(f0.w);
            av[4] = (short)f2bf(f1.x); av[5] = (short)f2bf(f1.y);
            av[6] = (short)f2bf(f1.z); av[7] = (short)f2bf(f1.w);
            a[kk] = av;
        }
    } else {
        const u16* A = (const u16*)Ap;
#pragma unroll
        for (int kk = 0; kk < 4; kk++)
            a[kk] = *(const short8*)(A + (size_t)mload * 128 + kk * 32 + quad * 8);
    }

    float4v acc[8], acc2[8];
#pragma unroll
    for (int tn = 0; tn < 8; tn++) {
        acc[tn] = (float4v){0.f, 0.f, 0.f, 0.f};
        if (DUAL) acc2[tn] = (float4v){0.f, 0.f, 0.f, 0.f};
    }

#pragma unroll
    for (int kk = 0; kk < 4; kk++) {
#pragma unroll
        for (int tn = 0; tn < 8; tn++) {
            short8 b = *(const short8*)(Bf + ((size_t)((kk * 8 + tn) * 64 + lane)) * 8);
            acc[tn] = __builtin_amdgcn_mfma_f32_16x16x32_bf16(a[kk], b, acc[tn], 0, 0, 0);
            if (DUAL) {
                short8 b2 = *(const short8*)(Bf2 + ((size_t)((kk * 8 + tn) * 64 + lane)) * 8);
                acc2[tn] = __builtin_amdgcn_mfma_f32_16x16x32_bf16(a[kk], b2, acc2[tn], 0, 0, 0);
            }
        }
    }

    float as0[4], as1[4], ad0[4], ad1[4];
    if (QUANT) {
#pragma unroll
        for (int hd = 0; hd < 4; hd++) {
            as0[hd] = a_src[hd * 32 + l15];
            as1[hd] = a_src[hd * 32 + 16 + l15];
            ad0[hd] = a_dst[hd * 32 + l15];
            ad1[hd] = a_dst[hd * 32 + 16 + l15];
        }
    }

#pragma unroll
    for (int rg = 0; rg < 4; rg++) {
        int gr = row0 + quad * 4 + rg;
        bool ok = (gr < M);
        if (!QUANT) {
            if (ok) {
#pragma unroll
                for (int tn = 0; tn < 8; tn++) {
                    C[(size_t)gr * 128 + tn * 16 + l15] = f2bf(acc[tn][rg]);
                    if (DUAL) C2[(size_t)gr * 128 + tn * 16 + l15] = f2bf(acc2[tn][rg]);
                }
            }
        } else {
            float amax = 0.f;
#pragma unroll
            for (int tn = 0; tn < 8; tn++) amax = fmaxf(amax, fabsf(acc[tn][rg]));
#pragma unroll
            for (int mm = 1; mm < 16; mm <<= 1) amax = fmaxf(amax, __shfl_xor(amax, mm, 64));
            float inv_s = (amax > 0.f) ? 127.f / amax : 0.f;
            if (ok) {
#pragma unroll
                for (int tn = 0; tn < 8; tn++) {
                    int q = (int)rintf(acc[tn][rg] * inv_s);
                    hq[(size_t)gr * 128 + tn * 16 + l15] = (char)q;
                }
                if (l15 == 0) alsc[(size_t)gr * 8 + 4] = amax * (1.f / 127.f);
            }
            float ps[4], pd[4];
#pragma unroll
            for (int hd = 0; hd < 4; hd++) {
                float c0 = acc[2 * hd][rg];
                float c1 = acc[2 * hd + 1][rg];
                ps[hd] = c0 * as0[hd] + c1 * as1[hd];
                pd[hd] = c0 * ad0[hd] + c1 * ad1[hd];
            }
#pragma unroll
            for (int mm = 1; mm < 16; mm <<= 1) {
#pragma unroll
                for (int hd = 0; hd < 4; hd++) {
                    ps[hd] += __shfl_xor(ps[hd], mm, 64);
                    pd[hd] += __shfl_xor(pd[hd], mm, 64);
                }
            }
            if (ok && l15 < 4) {
                float vs = (l15 == 0) ? ps[0] : (l15 == 1) ? ps[1] : (l15 == 2) ? ps[2] : ps[3];
                float vd = (l15 == 0) ? pd[0] : (l15 == 1) ? pd[1] : (l15 == 2) ? pd[2] : pd[3];
                alsc[(size_t)gr * 8 + l15] = vs;
                al_d[gr * 4 + l15] = vd;
            }
        }
    }
}

// ---------------- fused aggregation: score + softmax + int8 gather, single pass ----------------
// per edge: s via readlane -> SGPR base addressing; w = exp(leaky(al_s[s][h] + al_d[n][h]));
// sumw inline (lane-redundant within head group); scale folded per edge.
template<bool XF32>
__global__ void k_agg(const int* __restrict__ row_ptr, const int* __restrict__ col_src,
                      const float* __restrict__ alsc, const float* __restrict__ al_d,
                      const char* __restrict__ hq,
                      const void* __restrict__ xin, u16* __restrict__ xout) {
    int node = blockIdx.x * 4 + (threadIdx.x >> 6);
    int lane = threadIdx.x & 63;
    int beg = row_ptr[node], end = row_ptr[node + 1];
    int hh = lane >> 4;                       // this lane's head
    float adst = al_d[node * 4 + hh];
    const char* hqp = hq + lane * 2;          // per-lane byte base

    float sumw = 0.f;
    float a0[2] = {0.f, 0.f};
    float a1[2] = {0.f, 0.f};

    int i = beg;
    for (; i + 8 <= end; i += 8) {
        int sv = col_src[i + (lane & 7)];
#pragma unroll
        for (int j = 0; j < 8; j++) {
            int s = __builtin_amdgcn_readlane(sv, j);        // SGPR
            const float* ap = alsc + (size_t)s * 8;
            float e = ap[hh] + adst;
            e = fmaxf(e, 0.2f * e);                          // leaky
            float w = __expf(e);
            sumw += w;
            float wsc = w * ap[4];
            u32 hv = *(const u16*)(hqp + (size_t)s * 128);
            a0[j & 1] += wsc * (float)(int)(signed char)(hv & 0xFF);
            a1[j & 1] += wsc * (float)(int)(signed char)(hv >> 8);
        }
    }
    for (; i < end; i++) {
        int s = __builtin_amdgcn_readfirstlane(col_src[i]);
        const float* ap = alsc + (size_t)s * 8;
        float e = ap[hh] + adst;
        e = fmaxf(e, 0.2f * e);
        float w = __expf(e);
        sumw += w;
        float wsc = w * ap[4];
        u32 hv = *(const u16*)(hqp + (size_t)s * 128);
        a0[0] += wsc * (float)(int)(signed char)(hv & 0xFF);
        a1[0] += wsc * (float)(int)(signed char)(hv >> 8);
    }

    float inv = 1.f / (sumw + 1e-10f);
    float acc0 = (a0[0] + a0[1]) * inv;
    float acc1 = (a1[0] + a1[1]) * inv;

    float r0, r1;
    if (XF32) {
        const float* x = (const float*)xin;
        float2 xv = *(const float2*)&x[(size_t)node * 128 + lane * 2];
        r0 = xv.x;
        r1 = xv.y;
    } else {
        const u16* x = (const u16*)xin;
        u32 xv = *(const u32*)&x[(size_t)node * 128 + lane * 2];
        r0 = bf2f(xv & 0xffff);
        r1 = bf2f(xv >> 16);
    }
    float o0 = ((acc0 > 0.f) ? acc0 : (__expf(acc0) - 1.f)) + r0;
    float o1 = ((acc1 > 0.f) ? acc1 : (__expf(acc1) - 1.f)) + r1;
    xout[(size_t)node * 128 + lane * 2]     = f2bf(o0);
    xout[(size_t)node * 128 + lane * 2 + 1] = f2bf(o1);
}

// ---------------- link predictor ----------------
__global__ void k_pair(const int* __restrict__ psrc, const int* __restrict__ pdst,
                       const u16* __restrict__ u, const u16* __restrict__ v,
                       const float* __restrict__ b1, const float* __restrict__ w2,
                       const float* __restrict__ b2, float* __restrict__ out) {
    int p = blockIdx.x * 4 + (threadIdx.x >> 6);
    int lane = threadIdx.x & 63;
    int s = psrc[p], d = pdst[p];
    float h0 = bf2f(u[(size_t)s * 128 + lane * 2])     + bf2f(v[(size_t)d * 128 + lane * 2])     + b1[lane * 2];
    float h1 = bf2f(u[(size_t)s * 128 + lane * 2 + 1]) + bf2f(v[(size_t)d * 128 + lane * 2 + 1]) + b1[lane * 2 + 1];
    h0 = (h0 > 0.f) ? h0 : 0.f;
    h1 = (h1 > 0.f) ? h1 : 0.f;
    float acc = h0 * w2[lane * 2] + h1 * w2[lane * 2 + 1];
#pragma unroll
    for (int m = 1; m < 64; m <<= 1) acc += __shfl_xor(acc, m, 64);
    if (lane == 0) out[p] = acc + b2[0];
}

extern "C" void kernel_launch(void* const* d_in, const int* in_sizes, int n_in,
                              void* d_out, int out_size, void* d_ws, size_t ws_size,
                              hipStream_t stream) {
    const float* embed  = (const float*)d_in[0];
    const float* W1     = (const float*)d_in[1];
    const float* a_src1 = (const float*)d_in[2];
    const float* a_dst1 = (const float*)d_in[3];
    const float* W2     = (const float*)d_in[4];
    const float* a_src2 = (const float*)d_in[5];
    const float* a_dst2 = (const float*)d_in[6];
    const float* lp_w1  = (const float*)d_in[7];
    const float* lp_b1  = (const float*)d_in[8];
    const float* lp_w2  = (const float*)d_in[9];
    const float* lp_b2  = (const float*)d_in[10];
    const int*   edge   = (const int*)d_in[11];
    const int*   lsrc   = (const int*)d_in[12];
    const int*   ldst   = (const int*)d_in[13];
    float* out = (float*)d_out;

    char* ws = (char*)d_ws;
    size_t off = 0;
    auto alloc = [&](size_t bytes) -> char* {
        char* p = ws + off;
        off += (bytes + 255) & ~(size_t)255;
        return p;
    };
    int*  row_ptr    = (int*)alloc((N_NODES + 1) * 4);
    int*  bucket_cur = (int*)alloc(NBUCKP * 4);
    int2* binned     = (int2*)alloc((size_t)NBUCKP * BUCK_CAP * 8);
    int*  col_src    = (int*)alloc((size_t)N_EDGES * 4);
    char* hq         = (char*)alloc((size_t)N_NODES * 128);
    float* alsc      = (float*)alloc((size_t)N_NODES * 8 * 4);
    float* al_d      = (float*)alloc((size_t)N_NODES * 4 * 4);
    u16*  x1         = (u16*)alloc((size_t)N_NODES * 128 * 2);
    u16*  z          = (u16*)alloc((size_t)N_NODES * 128 * 2);
    u16*  uu         = (u16*)alloc((size_t)N_NODES * 128 * 2);
    u16*  vv         = (u16*)alloc((size_t)N_NODES * 128 * 2);
    u16*  Bf1        = (u16*)alloc(128 * 128 * 2);
    u16*  Bf2        = (u16*)alloc(128 * 128 * 2);
    u16*  BfA        = (u16*)alloc(128 * 128 * 2);
    u16*  BfB        = (u16*)alloc(128 * 128 * 2);

    const int* esrc = edge;
    const int* edst = edge + N_EDGES;
    const int GB = (N_NODES + 63) / 64;

    k_prepB4<<<33, 256, 0, stream>>>(W1, W2, lp_w1, lp_w1 + 128 * 128, Bf1, Bf2, BfA, BfB, bucket_cur);

    k_bin <<<BIN_GRID, 256, 0, stream>>>(esrc, edst, bucket_cur, binned);
    k_sort<<<NB_USED, 512, 0, stream>>>(binned, bucket_cur, row_ptr, col_src);

    // layer 1: hq = int8(embed @ W1), fused alpha+scale pack
    k_gemm<true, false, true><<<GB, 256, 0, stream>>>(embed, Bf1, nullptr, nullptr, nullptr,
                                                      hq, alsc, a_src1, a_dst1, al_d, N_NODES);
    k_agg<true><<<N_NODES / 4, 256, 0, stream>>>(row_ptr, col_src, alsc, al_d, hq, embed, x1);
    // layer 2
    k_gemm<false, false, true><<<GB, 256, 0, stream>>>(x1, Bf2, nullptr, nullptr, nullptr,
                                                       hq, alsc, a_src2, a_dst2, al_d, N_NODES);
    k_agg<false><<<N_NODES / 4, 256, 0, stream>>>(row_ptr, col_src, alsc, al_d, hq, x1, z);
    // link predictor
    k_gemm<false, true, false><<<GB, 256, 0, stream>>>(z, BfA, BfB, uu, vv,
                                                       nullptr, nullptr, nullptr, nullptr, nullptr, N_NODES);
    k_pair<<<N_PAIRS / 4, 256, 0, stream>>>(lsrc, ldst, uu, vv, lp_b1, lp_w2, lp_b2, out);
}